// Round 21
// baseline (118.944 us; speedup 1.0000x reference)
//
#include <hip/hip_runtime.h>
#include <hip/hip_bf16.h>
#include <hip/hip_fp16.h>
#include <math.h>

constexpr int Bn = 8, Cn = 256, Hn = 64, Wn = 64, Fn = 256, Kn = 9;
constexpr int HWn = Hn * Wn;               // 4096
constexpr int NM = Bn * Kn * HWn;          // 294912 meta entries (int4 each)
constexpr int NCH = 4;                     // c-split for offconv partials

using frag_ab = __attribute__((ext_vector_type(8))) short;     // 8 bf16
using frag_h  = __attribute__((ext_vector_type(8))) _Float16;  // 8 fp16
using f32x4   = __attribute__((ext_vector_type(4))) float;

__device__ inline ushort f2bf(float f) {
    union { float f; uint32_t u; } un{f};
    return (ushort)((un.u + 0x7FFF + ((un.u >> 16) & 1)) >> 16);   // RNE
}
__device__ inline ushort f2h(float f) {
    __half h = __float2half_rn(f);
    return *reinterpret_cast<ushort*>(&h);
}

// ---- Kernel 1: pack offset/mask weights (27 rows, pad to 32) as A-frags ----
__global__ __launch_bounds__(256) void wpack27(const float* __restrict__ wo,
                                               const float* __restrict__ wm,
                                               ushort* __restrict__ wA) {
    int i = blockIdx.x * 256 + threadIdx.x;
    if (i >= 73728) return;
    int ci = i & 7, l = (i >> 3) & 63, mt = (i >> 9) & 1, cblk = (i >> 10) & 7, tap = i >> 13;
    int m = mt * 16 + (l & 15);
    int c = cblk * 32 + ((l >> 4) & 3) * 8 + ci;
    float v = 0.f;
    if (m < 18)      v = wo[(m * Cn + c) * 9 + tap];
    else if (m < 27) v = wm[((m - 18) * Cn + c) * 9 + tap];
    wA[i] = f2bf(v);
}

// ---- Kernel 2a: offset/mask conv via MFMA (bf16), split over C -------------
__global__ __launch_bounds__(256) void offconv27(const float* __restrict__ x,
                                                 const ushort* __restrict__ wA,
                                                 float* __restrict__ part) {
    __shared__ ushort xs[4][66][40];
    const int t = threadIdx.x;
    const int l = t & 63, w = t >> 6;
    const int li = l & 15, lg = l >> 4;
    const int rb = blockIdx.x, ch = blockIdx.y, b = blockIdx.z;
    const int h0 = rb * 2;
    const int rw = w >> 1, pt0 = (w & 1) * 2;

    f32x4 acc[2][2];
#pragma unroll
    for (int mt = 0; mt < 2; ++mt)
#pragma unroll
        for (int q = 0; q < 2; ++q) acc[mt][q] = (f32x4)0.f;

    const float* xb = x + (size_t)b * Cn * HWn;

#pragma unroll 1
    for (int cc = 0; cc < 2; ++cc) {
        const int cbase = ch * 64 + cc * 32;
        __syncthreads();
        for (int j = t; j < 1056; j += 256) {
            int cq = j / 264;
            int rem = j - cq * 264;
            int r = rem / 66, col = rem - r * 66;
            int rg = h0 - 1 + r, cg = col - 1;
            ushort u[8];
            if ((unsigned)rg < (unsigned)Hn && (unsigned)cg < (unsigned)Wn) {
                const float* xp = xb + (size_t)(cbase + cq * 8) * HWn + (rg << 6) + cg;
#pragma unroll
                for (int jj = 0; jj < 8; ++jj) u[jj] = f2bf(xp[(size_t)jj * HWn]);
            } else {
#pragma unroll
                for (int jj = 0; jj < 8; ++jj) u[jj] = 0;
            }
            *(int4*)&xs[r][col][cq * 8] =
                make_int4(u[0] | (u[1] << 16), u[2] | (u[3] << 16),
                          u[4] | (u[5] << 16), u[6] | (u[7] << 16));
        }
        __syncthreads();
        const int cblk = ch * 2 + cc;
#pragma unroll
        for (int tap = 0; tap < 9; ++tap) {
            const int ky = tap / 3, kx = tap - 3 * (tap / 3);
            frag_ab a0 = *(const frag_ab*)(wA + (size_t)((tap * 8 + cblk) * 2) * 512 + l * 8);
            frag_ab a1 = *(const frag_ab*)(wA + (size_t)((tap * 8 + cblk) * 2 + 1) * 512 + l * 8);
#pragma unroll
            for (int q = 0; q < 2; ++q) {
                frag_ab bf = *(const frag_ab*)&xs[rw + ky][(pt0 + q) * 16 + li + kx][lg * 8];
                acc[0][q] = __builtin_amdgcn_mfma_f32_16x16x32_bf16(a0, bf, acc[0][q], 0, 0, 0);
                acc[1][q] = __builtin_amdgcn_mfma_f32_16x16x32_bf16(a1, bf, acc[1][q], 0, 0, 0);
            }
        }
    }

    const int h = h0 + rw;
#pragma unroll
    for (int mt = 0; mt < 2; ++mt)
#pragma unroll
        for (int j = 0; j < 4; ++j) {
            int m = mt * 16 + lg * 4 + j;
            if (m < 27) {
#pragma unroll
                for (int q = 0; q < 2; ++q) {
                    int pixel = (pt0 + q) * 16 + li;
                    part[((size_t)((ch * Bn + b) * 27 + m) << 12) + (h << 6) + pixel] =
                        acc[mt][q][j];
                }
            }
        }
}

// ---- Kernel 2b: per-k partial reduce + packed sampling metadata ------------
// mpack[q] = {i00|i01<<16, i10|i11<<16, half2(w00,w01), half2(w10,w11)}
__global__ __launch_bounds__(256) void metafin9(const float* __restrict__ part,
                                                int4* __restrict__ mpack) {
    const int k = blockIdx.y;
    const int idx = blockIdx.x * 256 + threadIdx.x;   // over Bn*HWn
    const int b = idx >> 12, p = idx & 4095;
    const int h = p >> 6, w = p & 63;

    float dy = 0.f, dx = 0.f, ms = 0.f;
#pragma unroll
    for (int ch = 0; ch < NCH; ++ch) {
        size_t base = ((size_t)((ch * Bn + b) * 27) << 12) + p;
        dy += part[base + ((size_t)(2 * k) << 12)];
        dx += part[base + ((size_t)(2 * k + 1) << 12)];
        ms += part[base + ((size_t)(18 + k) << 12)];
    }
    float m = 1.f / (1.f + expf(-ms));
    float yy = (float)(h + k / 3 - 1) + dy;
    float xx = (float)(w + k % 3 - 1) + dx;
    float y0f = floorf(yy), x0f = floorf(xx);
    float wy = yy - y0f, wx = xx - x0f;
    int y0 = (int)y0f, x0 = (int)x0f;
    int y1 = y0 + 1, x1 = x0 + 1;
    bool vy0 = (unsigned)y0 < (unsigned)Hn;
    bool vx0 = (unsigned)x0 < (unsigned)Wn;
    bool vy1 = (unsigned)y1 < (unsigned)Hn;
    bool vx1 = (unsigned)x1 < (unsigned)Wn;
    int cy0 = min(max(y0, 0), Hn - 1), cx0 = min(max(x0, 0), Wn - 1);
    int cy1 = min(max(y1, 0), Hn - 1), cx1 = min(max(x1, 0), Wn - 1);
    float w00 = (vy0 && vx0) ? (1.f - wy) * (1.f - wx) * m : 0.f;
    float w01 = (vy0 && vx1) ? (1.f - wy) * wx * m : 0.f;
    float w10 = (vy1 && vx0) ? wy * (1.f - wx) * m : 0.f;
    float w11 = (vy1 && vx1) ? wy * wx * m : 0.f;
    int i00 = (cy0 << 6) + cx0, i01 = (cy0 << 6) + cx1;
    int i10 = (cy1 << 6) + cx0, i11 = (cy1 << 6) + cx1;
    union { struct { __half a, bh; } h; int i; } pz, pw;
    pz.h.a = __float2half_rn(w00); pz.h.bh = __float2half_rn(w01);
    pw.h.a = __float2half_rn(w10); pw.h.bh = __float2half_rn(w11);
    int q = ((b * 9 + k) << 12) + p;
    mpack[q] = make_int4(i00 | (i01 << 16), i10 | (i11 << 16), pz.i, pw.i);
}

// ---- Kernel 2c: fused wtrans2 + xpose (runs AFTER part is dead) ------------
__global__ __launch_bounds__(256) void packBX(const float* __restrict__ wd,
                                              const float* __restrict__ x,
                                              ushort* __restrict__ wB,
                                              __half2* __restrict__ xh) {
    const int bid = blockIdx.x, t = threadIdx.x;
    if (bid < 2304) {                       // wtrans2: deform weights -> fp16 A-frags
        int i = bid * 256 + t;
        int ci = i & 7, fi = (i >> 3) & 15, G = (i >> 7) & 31, ft = (i >> 12) & 15, k = i >> 16;
        int f = ft * 16 + fi, c = G * 8 + ci;
        wB[i] = f2h(wd[(f * Cn + c) * 9 + k]);
    } else {                                // xpose: x NCHW f32 -> NHWC fp16-pair
        int i = (bid - 2304) * 256 + t;     // over Bn*4*HWn
        int p = i & 4095, q = (i >> 12) & 3, b = i >> 14;
        const float* xp = x + (size_t)b * Cn * HWn + p;
        __half2* op = xh + (((size_t)b * 4096 + p) << 7) + q * 32;
#pragma unroll
        for (int j = 0; j < 32; ++j) {
            int c = q * 64 + 2 * j;
            op[j] = __float22half2_rn(make_float2(xp[(size_t)c * HWn],
                                                  xp[(size_t)(c + 1) * HWn]));
        }
    }
}

// ---- Kernel 3: fp16 MFMA deformable-conv GEMM, 64f x 32px wave tiles -------
// Same staging/swizzle/18-barrier loop as round-18; COMPUTE rearranged so each
// bq LDS read feeds 4 A-frags (fblk = w&3 owns 64 f, ph = w>>2 owns 32 px):
// ds_read_b128 per wave per step 8 -> 4 (LDS was the largest component).
__global__ __launch_bounds__(512, 4) void dconv(const uint32_t* __restrict__ xh,
                                                const ushort* __restrict__ wB,
                                                const int4* __restrict__ mpack,
                                                float* __restrict__ out) {
    __shared__ ushort sl[2][2][64][64];   // [dbuf][sub-step][pixel][64c]
    __shared__ int4 ml[9][64];
    const int t = threadIdx.x;
    const int l = t & 63, w = t >> 6;
    const int li = l & 15, lg = l >> 4;
    const int pu = (w << 3) + (l >> 3);  // staging pixel (one per lane)
    const int g  = l & 7;                // 16B channel-group (8 channels)
    const int fblk = w & 3;              // 64-f block (4 ft tiles)
    const int ph = w >> 2;               // pixel half (32 px)
    const int b = blockIdx.x;
    const int p0 = blockIdx.y << 6;

    f32x4 acc[4][2];                     // [ftl][q]
#pragma unroll
    for (int a = 0; a < 4; ++a)
#pragma unroll
        for (int q = 0; q < 2; ++q) acc[a][q] = (f32x4)0.f;

    const uint32_t* xb = xh + ((size_t)b << 19);   // b*4096*128 dwords

    for (int j = t; j < 576; j += 512)
        ml[j >> 6][j & 63] = mpack[((b * 9 + (j >> 6)) << 12) + p0 + (j & 63)];
    __syncthreads();

    auto STAGE = [&](int s) {
        const int k = s % 9, ch = s / 9;
        const int4 m = ml[k][pu];
        const int i00 = m.x & 0xFFFF, i01 = ((unsigned)m.x) >> 16;
        const int i10 = m.y & 0xFFFF, i11 = ((unsigned)m.y) >> 16;
        union { int i; __half2 h; } uz, uw;
        uz.i = m.z; uw.i = m.w;
        const uint32_t* base = xb + (ch << 5) + (g << 2);
        uint4 v00 = *(const uint4*)(base + (size_t)i00 * 128);
        uint4 v01 = *(const uint4*)(base + (size_t)i01 * 128);
        uint4 v10 = *(const uint4*)(base + (size_t)i10 * 128);
        uint4 v11 = *(const uint4*)(base + (size_t)i11 * 128);
        const __half2 w00 = __half2half2(__low2half(uz.h));
        const __half2 w01 = __half2half2(__high2half(uz.h));
        const __half2 w10 = __half2half2(__low2half(uw.h));
        const __half2 w11 = __half2half2(__high2half(uw.h));
        uint4 rr;
        {
            __half2 r = __hmul2(w00, *(__half2*)&v00.x);
            r = __hfma2(w01, *(__half2*)&v01.x, r);
            r = __hfma2(w10, *(__half2*)&v10.x, r);
            r = __hfma2(w11, *(__half2*)&v11.x, r);
            rr.x = *(uint32_t*)&r;
        }
        {
            __half2 r = __hmul2(w00, *(__half2*)&v00.y);
            r = __hfma2(w01, *(__half2*)&v01.y, r);
            r = __hfma2(w10, *(__half2*)&v10.y, r);
            r = __hfma2(w11, *(__half2*)&v11.y, r);
            rr.y = *(uint32_t*)&r;
        }
        {
            __half2 r = __hmul2(w00, *(__half2*)&v00.z);
            r = __hfma2(w01, *(__half2*)&v01.z, r);
            r = __hfma2(w10, *(__half2*)&v10.z, r);
            r = __hfma2(w11, *(__half2*)&v11.z, r);
            rr.z = *(uint32_t*)&r;
        }
        {
            __half2 r = __hmul2(w00, *(__half2*)&v00.w);
            r = __hfma2(w01, *(__half2*)&v01.w, r);
            r = __hfma2(w10, *(__half2*)&v10.w, r);
            r = __hfma2(w11, *(__half2*)&v11.w, r);
            rr.w = *(uint32_t*)&r;
        }
        *(uint4*)&sl[(s >> 1) & 1][s & 1][pu][(g ^ (pu & 7)) << 3] = rr;
    };

    auto COMPUTE = [&](int s) {
        const int k = s % 9, ch = s / 9;
        const ushort* wp = wB + ((size_t)((k * 16 + fblk * 4) * 512 + ch * 128)) * 8;
#pragma unroll
        for (int h = 0; h < 2; ++h) {
            frag_h bq[2];
#pragma unroll
            for (int q = 0; q < 2; ++q)
                bq[q] = *(const frag_h*)&sl[(s >> 1) & 1][s & 1][(ph * 2 + q) * 16 + li]
                                          [((((h << 2) | lg) ^ (l & 7)) << 3)];
#pragma unroll
            for (int ftl = 0; ftl < 4; ++ftl) {
                frag_h a = *(const frag_h*)(wp + (size_t)(ftl * 512 + h * 64 + l) * 8);
#pragma unroll
                for (int q = 0; q < 2; ++q)
                    acc[ftl][q] = __builtin_amdgcn_mfma_f32_16x16x32_f16(
                        a, bq[q], acc[ftl][q], 0, 0, 0);
            }
        }
    };

    STAGE(0);
    STAGE(1);
    __syncthreads();
#pragma unroll 1
    for (int s = 0; s < 36; s += 2) {
        if (s + 2 < 36) {
            STAGE(s + 2);
            STAGE(s + 3);
        }
        COMPUTE(s);
        COMPUTE(s + 1);
        __syncthreads();
    }

    float* ob = out + (size_t)b * Fn * HWn + p0;
#pragma unroll
    for (int ftl = 0; ftl < 4; ++ftl)
#pragma unroll
        for (int j = 0; j < 4; ++j) {
            int f = fblk * 64 + ftl * 16 + lg * 4 + j;
#pragma unroll
            for (int q = 0; q < 2; ++q)
                ob[(size_t)f * HWn + (ph * 2 + q) * 16 + li] = acc[ftl][q][j];
        }
}

extern "C" void kernel_launch(void* const* d_in, const int* in_sizes, int n_in,
                              void* d_out, int out_size, void* d_ws, size_t ws_size,
                              hipStream_t stream) {
    const float* x  = (const float*)d_in[0];
    const float* wo = (const float*)d_in[1];
    const float* wm = (const float*)d_in[2];
    const float* wd = (const float*)d_in[3];
    float* out = (float*)d_out;

    // ws: [mpack 4.72MB][region 18MB: part(14.16MB, consumed by metafin9) THEN
    //      wB(1.18MB)+xh(16.78MB) written by packBX][wA27 147KB].
    // ORDER MATTERS: packBX must run after metafin9 (part overlays wB+xh).
    int4*     mpack = (int4*)d_ws;
    char*     region = (char*)d_ws + (size_t)NM * 16;
    float*    part  = (float*)region;
    ushort*   wBp   = (ushort*)region;
    __half2*  xhh   = (__half2*)(region + 1179648);
    uint32_t* xhu   = (uint32_t*)(region + 1179648);
    ushort*   wA27  = (ushort*)(region + 18874368);

    wpack27<<<dim3(288), dim3(256), 0, stream>>>(wo, wm, wA27);
    offconv27<<<dim3(32, NCH, Bn), dim3(256), 0, stream>>>(x, wA27, part);
    metafin9<<<dim3(Bn * HWn / 256, 9), dim3(256), 0, stream>>>(part, mpack);
    packBX<<<dim3(2816), dim3(256), 0, stream>>>(wd, x, wBp, xhh);
    dconv<<<dim3(Bn, HWn / 64), dim3(512), 0, stream>>>(xhu, wBp, mpack, out);
}

// Round 22
// 110.166 us; speedup vs baseline: 1.0797x; 1.0797x over previous
//
#include <hip/hip_runtime.h>
#include <hip/hip_bf16.h>
#include <hip/hip_fp16.h>
#include <math.h>

constexpr int Bn = 8, Cn = 256, Hn = 64, Wn = 64, Fn = 256, Kn = 9;
constexpr int HWn = Hn * Wn;               // 4096
constexpr int NM = Bn * Kn * HWn;          // 294912 meta entries (int4 each)

using frag_h  = __attribute__((ext_vector_type(8))) _Float16;  // 8 fp16
using f32x4   = __attribute__((ext_vector_type(4))) float;

__device__ inline ushort f2h(float f) {
    __half h = __float2half_rn(f);
    return *reinterpret_cast<ushort*>(&h);
}

// ---- Kernel 1: fused packers (all independent; no overlay hazards) ---------
// bid<2304: wtrans2 (deform w -> fp16 A-frags); <2592: wpack27 (offset/mask w
// -> fp16 A-frags, 27 rows pad 32); else xpose (x NCHW f32 -> NHWC fp16-pair).
__global__ __launch_bounds__(256) void packall(const float* __restrict__ wd,
                                               const float* __restrict__ wo,
                                               const float* __restrict__ wm,
                                               const float* __restrict__ x,
                                               ushort* __restrict__ wB,
                                               ushort* __restrict__ wA,
                                               __half2* __restrict__ xh) {
    const int bid = blockIdx.x, t = threadIdx.x;
    if (bid < 2304) {
        int i = bid * 256 + t;
        int ci = i & 7, fi = (i >> 3) & 15, G = (i >> 7) & 31, ft = (i >> 12) & 15, k = i >> 16;
        int f = ft * 16 + fi, c = G * 8 + ci;
        wB[i] = f2h(wd[(f * Cn + c) * 9 + k]);
    } else if (bid < 2592) {
        int i = (bid - 2304) * 256 + t;
        int ci = i & 7, l = (i >> 3) & 63, mt = (i >> 9) & 1, cblk = (i >> 10) & 7, tap = i >> 13;
        int m = mt * 16 + (l & 15);
        int c = cblk * 32 + ((l >> 4) & 3) * 8 + ci;
        float v = 0.f;
        if (m < 18)      v = wo[(m * Cn + c) * 9 + tap];
        else if (m < 27) v = wm[((m - 18) * Cn + c) * 9 + tap];
        wA[i] = f2h(v);
    } else {
        int i = (bid - 2592) * 256 + t;     // over Bn*4*HWn
        int p = i & 4095, q = (i >> 12) & 3, b = i >> 14;
        const float* xp = x + (size_t)b * Cn * HWn + p;
        __half2* op = xh + (((size_t)b * 4096 + p) << 7) + q * 32;
#pragma unroll
        for (int j = 0; j < 32; ++j) {
            int c = q * 64 + 2 * j;
            op[j] = __float22half2_rn(make_float2(xp[(size_t)c * HWn],
                                                  xp[(size_t)(c + 1) * HWn]));
        }
    }
}

// ---- Kernel 2: fused offset/mask conv (fp16 MFMA, full C) + metadata -------
// Block = (rb: 2 rows, b), 4 waves; wave w: row rw=w>>1, pixel quarter pt0.
// Loops 8x 32-channel chunks from xh (coalesced); epilogue exchanges the 27
// conv outputs via LDS and computes packed sampling metadata -> mpack.
__global__ __launch_bounds__(256) void offmeta(const uint32_t* __restrict__ xh,
                                               const ushort* __restrict__ wA,
                                               int4* __restrict__ mpack) {
    __shared__ ushort xs[4][66][36];      // 32c chunk, pad 36 (2-way max)
    __shared__ float macc[32][128];       // [m][pixel-in-block]
    const int t = threadIdx.x;
    const int l = t & 63, w = t >> 6;
    const int li = l & 15, lg = l >> 4;
    const int rb = blockIdx.x, b = blockIdx.y;
    const int h0 = rb * 2;
    const int rw = w >> 1, pt0 = (w & 1) * 2;

    f32x4 acc[2][2];
#pragma unroll
    for (int mt = 0; mt < 2; ++mt)
#pragma unroll
        for (int q = 0; q < 2; ++q) acc[mt][q] = (f32x4)0.f;

    const uint32_t* xbb = xh + ((size_t)b << 19);   // b*4096*128 dwords

#pragma unroll 1
    for (int cs = 0; cs < 8; ++cs) {
        __syncthreads();
        for (int j = t; j < 1056; j += 256) {       // 4x66 px x 4 uint4 (32c)
            int pj = j >> 2, qd = j & 3;
            int r = pj / 66, col = pj - r * 66;
            int rg = h0 - 1 + r, cg = col - 1;
            uint4 v = make_uint4(0, 0, 0, 0);
            if ((unsigned)rg < (unsigned)Hn && (unsigned)cg < (unsigned)Wn)
                v = *(const uint4*)(xbb + ((size_t)((rg << 6) + cg) << 7) + cs * 16 + qd * 4);
            *(uint4*)&xs[r][col][qd * 8] = v;
        }
        __syncthreads();
#pragma unroll
        for (int tap = 0; tap < 9; ++tap) {
            const int ky = tap / 3, kx = tap - 3 * (tap / 3);
            frag_h a0 = *(const frag_h*)(wA + (size_t)((tap * 8 + cs) * 2) * 512 + l * 8);
            frag_h a1 = *(const frag_h*)(wA + (size_t)((tap * 8 + cs) * 2 + 1) * 512 + l * 8);
#pragma unroll
            for (int q = 0; q < 2; ++q) {
                frag_h bf = *(const frag_h*)&xs[rw + ky][(pt0 + q) * 16 + li + kx][lg * 8];
                acc[0][q] = __builtin_amdgcn_mfma_f32_16x16x32_f16(a0, bf, acc[0][q], 0, 0, 0);
                acc[1][q] = __builtin_amdgcn_mfma_f32_16x16x32_f16(a1, bf, acc[1][q], 0, 0, 0);
            }
        }
    }

    __syncthreads();
#pragma unroll
    for (int mt = 0; mt < 2; ++mt)
#pragma unroll
        for (int j = 0; j < 4; ++j) {
            int m = mt * 16 + lg * 4 + j;
#pragma unroll
            for (int q = 0; q < 2; ++q)
                macc[m][rw * 64 + (pt0 + q) * 16 + li] = acc[mt][q][j];
        }
    __syncthreads();

    for (int it = t; it < 1152; it += 256) {        // 9 k x 128 px
        int k = it >> 7, pxl = it & 127;
        float dy = macc[2 * k][pxl];
        float dx = macc[2 * k + 1][pxl];
        float ms = macc[18 + k][pxl];
        int h = h0 + (pxl >> 6), wc = pxl & 63;
        float m = 1.f / (1.f + expf(-ms));
        float yy = (float)(h + k / 3 - 1) + dy;
        float xx = (float)(wc + k % 3 - 1) + dx;
        float y0f = floorf(yy), x0f = floorf(xx);
        float wy = yy - y0f, wx = xx - x0f;
        int y0 = (int)y0f, x0 = (int)x0f;
        int y1 = y0 + 1, x1 = x0 + 1;
        bool vy0 = (unsigned)y0 < (unsigned)Hn;
        bool vx0 = (unsigned)x0 < (unsigned)Wn;
        bool vy1 = (unsigned)y1 < (unsigned)Hn;
        bool vx1 = (unsigned)x1 < (unsigned)Wn;
        int cy0 = min(max(y0, 0), Hn - 1), cx0 = min(max(x0, 0), Wn - 1);
        int cy1 = min(max(y1, 0), Hn - 1), cx1 = min(max(x1, 0), Wn - 1);
        float w00 = (vy0 && vx0) ? (1.f - wy) * (1.f - wx) * m : 0.f;
        float w01 = (vy0 && vx1) ? (1.f - wy) * wx * m : 0.f;
        float w10 = (vy1 && vx0) ? wy * (1.f - wx) * m : 0.f;
        float w11 = (vy1 && vx1) ? wy * wx * m : 0.f;
        int i00 = (cy0 << 6) + cx0, i01 = (cy0 << 6) + cx1;
        int i10 = (cy1 << 6) + cx0, i11 = (cy1 << 6) + cx1;
        union { struct { __half a, bh; } hh; int i; } pz, pw;
        pz.hh.a = __float2half_rn(w00); pz.hh.bh = __float2half_rn(w01);
        pw.hh.a = __float2half_rn(w10); pw.hh.bh = __float2half_rn(w11);
        int p = (h << 6) + wc;
        mpack[((b * 9 + k) << 12) + p] =
            make_int4(i00 | (i01 << 16), i10 | (i11 << 16), pz.i, pw.i);
    }
}

// ---- Kernel 3: fp16 MFMA deformable-conv GEMM (round-18 champion, 63.2us) --
__global__ __launch_bounds__(512, 4) void dconv(const uint32_t* __restrict__ xh,
                                                const ushort* __restrict__ wB,
                                                const int4* __restrict__ mpack,
                                                float* __restrict__ out) {
    __shared__ ushort sl[2][2][64][64];   // [dbuf][sub-step][pixel][64c]
    __shared__ int4 ml[9][64];
    const int t = threadIdx.x;
    const int l = t & 63, w = t >> 6;
    const int li = l & 15, lg = l >> 4;
    const int pu = (w << 3) + (l >> 3);  // staging pixel (one per lane)
    const int g  = l & 7;                // 16B channel-group (8 channels)
    const int b = blockIdx.x;
    const int p0 = blockIdx.y << 6;

    f32x4 acc[2][4];
#pragma unroll
    for (int a = 0; a < 2; ++a)
#pragma unroll
        for (int q = 0; q < 4; ++q) acc[a][q] = (f32x4)0.f;

    const uint32_t* xb = xh + ((size_t)b << 19);   // b*4096*128 dwords

    for (int j = t; j < 576; j += 512)
        ml[j >> 6][j & 63] = mpack[((b * 9 + (j >> 6)) << 12) + p0 + (j & 63)];
    __syncthreads();

    auto STAGE = [&](int s) {
        const int k = s % 9, ch = s / 9;
        const int4 m = ml[k][pu];
        const int i00 = m.x & 0xFFFF, i01 = ((unsigned)m.x) >> 16;
        const int i10 = m.y & 0xFFFF, i11 = ((unsigned)m.y) >> 16;
        union { int i; __half2 h; } uz, uw;
        uz.i = m.z; uw.i = m.w;
        const uint32_t* base = xb + (ch << 5) + (g << 2);
        uint4 v00 = *(const uint4*)(base + (size_t)i00 * 128);
        uint4 v01 = *(const uint4*)(base + (size_t)i01 * 128);
        uint4 v10 = *(const uint4*)(base + (size_t)i10 * 128);
        uint4 v11 = *(const uint4*)(base + (size_t)i11 * 128);
        const __half2 w00 = __half2half2(__low2half(uz.h));
        const __half2 w01 = __half2half2(__high2half(uz.h));
        const __half2 w10 = __half2half2(__low2half(uw.h));
        const __half2 w11 = __half2half2(__high2half(uw.h));
        uint4 rr;
        {
            __half2 r = __hmul2(w00, *(__half2*)&v00.x);
            r = __hfma2(w01, *(__half2*)&v01.x, r);
            r = __hfma2(w10, *(__half2*)&v10.x, r);
            r = __hfma2(w11, *(__half2*)&v11.x, r);
            rr.x = *(uint32_t*)&r;
        }
        {
            __half2 r = __hmul2(w00, *(__half2*)&v00.y);
            r = __hfma2(w01, *(__half2*)&v01.y, r);
            r = __hfma2(w10, *(__half2*)&v10.y, r);
            r = __hfma2(w11, *(__half2*)&v11.y, r);
            rr.y = *(uint32_t*)&r;
        }
        {
            __half2 r = __hmul2(w00, *(__half2*)&v00.z);
            r = __hfma2(w01, *(__half2*)&v01.z, r);
            r = __hfma2(w10, *(__half2*)&v10.z, r);
            r = __hfma2(w11, *(__half2*)&v11.z, r);
            rr.z = *(uint32_t*)&r;
        }
        {
            __half2 r = __hmul2(w00, *(__half2*)&v00.w);
            r = __hfma2(w01, *(__half2*)&v01.w, r);
            r = __hfma2(w10, *(__half2*)&v10.w, r);
            r = __hfma2(w11, *(__half2*)&v11.w, r);
            rr.w = *(uint32_t*)&r;
        }
        *(uint4*)&sl[(s >> 1) & 1][s & 1][pu][(g ^ (pu & 7)) << 3] = rr;
    };

    auto COMPUTE = [&](int s) {
        const int k = s % 9, ch = s / 9;
        const ushort* wp = wB + ((size_t)((k * 16 + 2 * w) * 512 + ch * 128)) * 8;
#pragma unroll
        for (int h = 0; h < 2; ++h) {
            frag_h bq[4];
#pragma unroll
            for (int pt = 0; pt < 4; ++pt)
                bq[pt] = *(const frag_h*)&sl[(s >> 1) & 1][s & 1][pt * 16 + li]
                                           [((((h << 2) | lg) ^ (l & 7)) << 3)];
#pragma unroll
            for (int ft = 0; ft < 2; ++ft) {
                frag_h a = *(const frag_h*)(wp + (size_t)(ft * 512 + h * 64 + l) * 8);
#pragma unroll
                for (int pt = 0; pt < 4; ++pt)
                    acc[ft][pt] = __builtin_amdgcn_mfma_f32_16x16x32_f16(
                        a, bq[pt], acc[ft][pt], 0, 0, 0);
            }
        }
    };

    STAGE(0);
    STAGE(1);
    __syncthreads();
#pragma unroll 1
    for (int s = 0; s < 36; s += 2) {
        if (s + 2 < 36) {
            STAGE(s + 2);
            STAGE(s + 3);
        }
        COMPUTE(s);
        COMPUTE(s + 1);
        __syncthreads();
    }

    float* ob = out + (size_t)b * Fn * HWn + p0;
#pragma unroll
    for (int ft = 0; ft < 2; ++ft)
#pragma unroll
        for (int j = 0; j < 4; ++j) {
            int f = w * 32 + ft * 16 + lg * 4 + j;
#pragma unroll
            for (int pt = 0; pt < 4; ++pt)
                ob[(size_t)f * HWn + pt * 16 + li] = acc[ft][pt][j];
        }
}

extern "C" void kernel_launch(void* const* d_in, const int* in_sizes, int n_in,
                              void* d_out, int out_size, void* d_ws, size_t ws_size,
                              hipStream_t stream) {
    const float* x  = (const float*)d_in[0];
    const float* wo = (const float*)d_in[1];
    const float* wm = (const float*)d_in[2];
    const float* wd = (const float*)d_in[3];
    float* out = (float*)d_out;

    // ws (no overlays): [mpack 4.72MB][wB 1.18MB][xh 16.78MB][wA27 147KB]
    //                   = 21.8MB total (< proven 23.74MB)
    int4*     mpack = (int4*)d_ws;
    ushort*   wBp   = (ushort*)((char*)d_ws + 4718592);
    __half2*  xhh   = (__half2*)((char*)d_ws + 5898240);
    uint32_t* xhu   = (uint32_t*)((char*)d_ws + 5898240);
    ushort*   wA27  = (ushort*)((char*)d_ws + 22675456);

    packall<<<dim3(3104), dim3(256), 0, stream>>>(wd, wo, wm, x, wBp, wA27, xhh);
    offmeta<<<dim3(32, Bn), dim3(256), 0, stream>>>(xhu, wA27, mpack);
    dconv<<<dim3(Bn, HWn / 64), dim3(512), 0, stream>>>(xhu, wBp, mpack, out);
}

// Round 23
// 96.583 us; speedup vs baseline: 1.2315x; 1.1406x over previous
//
#include <hip/hip_runtime.h>
#include <hip/hip_bf16.h>
#include <hip/hip_fp16.h>
#include <math.h>

constexpr int Bn = 8, Cn = 256, Hn = 64, Wn = 64, Fn = 256, Kn = 9;
constexpr int HWn = Hn * Wn;               // 4096
constexpr int NM = Bn * Kn * HWn;          // 294912 meta entries (int4 each)

using frag_h  = __attribute__((ext_vector_type(8))) _Float16;  // 8 fp16
using f32x4   = __attribute__((ext_vector_type(4))) float;

__device__ inline ushort f2h(float f) {
    __half h = __float2half_rn(f);
    return *reinterpret_cast<ushort*>(&h);
}

// ---- Kernel 1: fused packers (all independent; no overlay hazards) ---------
__global__ __launch_bounds__(256) void packall(const float* __restrict__ wd,
                                               const float* __restrict__ wo,
                                               const float* __restrict__ wm,
                                               const float* __restrict__ x,
                                               ushort* __restrict__ wB,
                                               ushort* __restrict__ wA,
                                               __half2* __restrict__ xh) {
    const int bid = blockIdx.x, t = threadIdx.x;
    if (bid < 2304) {                       // deform w -> fp16 A-frags
        int i = bid * 256 + t;
        int ci = i & 7, fi = (i >> 3) & 15, G = (i >> 7) & 31, ft = (i >> 12) & 15, k = i >> 16;
        int f = ft * 16 + fi, c = G * 8 + ci;
        wB[i] = f2h(wd[(f * Cn + c) * 9 + k]);
    } else if (bid < 2592) {                // offset/mask w -> fp16 A-frags
        int i = (bid - 2304) * 256 + t;
        int ci = i & 7, l = (i >> 3) & 63, mt = (i >> 9) & 1, cblk = (i >> 10) & 7, tap = i >> 13;
        int m = mt * 16 + (l & 15);
        int c = cblk * 32 + ((l >> 4) & 3) * 8 + ci;
        float v = 0.f;
        if (m < 18)      v = wo[(m * Cn + c) * 9 + tap];
        else if (m < 27) v = wm[((m - 18) * Cn + c) * 9 + tap];
        wA[i] = f2h(v);
    } else {                                // x NCHW f32 -> NHWC fp16-pair
        int i = (bid - 2592) * 256 + t;     // over Bn*4*HWn
        int p = i & 4095, q = (i >> 12) & 3, b = i >> 14;
        const float* xp = x + (size_t)b * Cn * HWn + p;
        __half2* op = xh + (((size_t)b * 4096 + p) << 7) + q * 32;
#pragma unroll
        for (int j = 0; j < 32; ++j) {
            int c = q * 64 + 2 * j;
            op[j] = __float22half2_rn(make_float2(xp[(size_t)c * HWn],
                                                  xp[(size_t)(c + 1) * HWn]));
        }
    }
}

// ---- Kernel 2: fused offset/mask conv (fp16 MFMA, full C) + metadata -------
// 512 thr / 8 waves; wave w: row rw=w>>2, quarter qt=w&3 (1 MFMA-pair/tap).
// Grid (b, rb): b fastest -> each XCD holds one batch's xh slice in L2.
__global__ __launch_bounds__(512) void offmeta(const uint32_t* __restrict__ xh,
                                               const ushort* __restrict__ wA,
                                               int4* __restrict__ mpack) {
    __shared__ ushort xs[4][66][36];      // 32c chunk, pad 36
    __shared__ float macc[32][128];       // [m][pixel-in-block]
    const int t = threadIdx.x;
    const int l = t & 63, w = t >> 6;
    const int li = l & 15, lg = l >> 4;
    const int b = blockIdx.x, rb = blockIdx.y;
    const int h0 = rb * 2;
    const int rw = w >> 2, qt = w & 3;

    f32x4 acc0 = (f32x4)0.f, acc1 = (f32x4)0.f;

    const uint32_t* xbb = xh + ((size_t)b << 19);   // b*4096*128 dwords

#pragma unroll 1
    for (int cs = 0; cs < 8; ++cs) {
        __syncthreads();
        for (int j = t; j < 1056; j += 512) {       // 4x66 px x 4 uint4 (32c)
            int pj = j >> 2, qd = j & 3;
            int r = pj / 66, col = pj - r * 66;
            int rg = h0 - 1 + r, cg = col - 1;
            uint4 v = make_uint4(0, 0, 0, 0);
            if ((unsigned)rg < (unsigned)Hn && (unsigned)cg < (unsigned)Wn)
                v = *(const uint4*)(xbb + ((size_t)((rg << 6) + cg) << 7) + cs * 16 + qd * 4);
            *(uint4*)&xs[r][col][qd * 8] = v;
        }
        __syncthreads();
#pragma unroll
        for (int tap = 0; tap < 9; ++tap) {
            const int ky = tap / 3, kx = tap - 3 * (tap / 3);
            frag_h a0 = *(const frag_h*)(wA + (size_t)((tap * 8 + cs) * 2) * 512 + l * 8);
            frag_h a1 = *(const frag_h*)(wA + (size_t)((tap * 8 + cs) * 2 + 1) * 512 + l * 8);
            frag_h bf = *(const frag_h*)&xs[rw + ky][qt * 16 + li + kx][lg * 8];
            acc0 = __builtin_amdgcn_mfma_f32_16x16x32_f16(a0, bf, acc0, 0, 0, 0);
            acc1 = __builtin_amdgcn_mfma_f32_16x16x32_f16(a1, bf, acc1, 0, 0, 0);
        }
    }

    __syncthreads();
#pragma unroll
    for (int j = 0; j < 4; ++j) {
        macc[lg * 4 + j][rw * 64 + qt * 16 + li] = acc0[j];
        macc[16 + lg * 4 + j][rw * 64 + qt * 16 + li] = acc1[j];
    }
    __syncthreads();

    for (int it = t; it < 1152; it += 512) {        // 9 k x 128 px
        int k = it >> 7, pxl = it & 127;
        float dy = macc[2 * k][pxl];
        float dx = macc[2 * k + 1][pxl];
        float ms = macc[18 + k][pxl];
        int h = h0 + (pxl >> 6), wc = pxl & 63;
        float m = 1.f / (1.f + expf(-ms));
        float yy = (float)(h + k / 3 - 1) + dy;
        float xx = (float)(wc + k % 3 - 1) + dx;
        float y0f = floorf(yy), x0f = floorf(xx);
        float wy = yy - y0f, wx = xx - x0f;
        int y0 = (int)y0f, x0 = (int)x0f;
        int y1 = y0 + 1, x1 = x0 + 1;
        bool vy0 = (unsigned)y0 < (unsigned)Hn;
        bool vx0 = (unsigned)x0 < (unsigned)Wn;
        bool vy1 = (unsigned)y1 < (unsigned)Hn;
        bool vx1 = (unsigned)x1 < (unsigned)Wn;
        int cy0 = min(max(y0, 0), Hn - 1), cx0 = min(max(x0, 0), Wn - 1);
        int cy1 = min(max(y1, 0), Hn - 1), cx1 = min(max(x1, 0), Wn - 1);
        float w00 = (vy0 && vx0) ? (1.f - wy) * (1.f - wx) * m : 0.f;
        float w01 = (vy0 && vx1) ? (1.f - wy) * wx * m : 0.f;
        float w10 = (vy1 && vx0) ? wy * (1.f - wx) * m : 0.f;
        float w11 = (vy1 && vx1) ? wy * wx * m : 0.f;
        int i00 = (cy0 << 6) + cx0, i01 = (cy0 << 6) + cx1;
        int i10 = (cy1 << 6) + cx0, i11 = (cy1 << 6) + cx1;
        union { struct { __half a, bh; } hh; int i; } pz, pw;
        pz.hh.a = __float2half_rn(w00); pz.hh.bh = __float2half_rn(w01);
        pw.hh.a = __float2half_rn(w10); pw.hh.bh = __float2half_rn(w11);
        int p = (h << 6) + wc;
        mpack[((b * 9 + k) << 12) + p] =
            make_int4(i00 | (i01 << 16), i10 | (i11 << 16), pz.i, pw.i);
    }
}

// ---- Kernel 3: fp16 MFMA deformable-conv GEMM (champion, 62.5us) -----------
__global__ __launch_bounds__(512, 4) void dconv(const uint32_t* __restrict__ xh,
                                                const ushort* __restrict__ wB,
                                                const int4* __restrict__ mpack,
                                                float* __restrict__ out) {
    __shared__ ushort sl[2][2][64][64];   // [dbuf][sub-step][pixel][64c]
    __shared__ int4 ml[9][64];
    const int t = threadIdx.x;
    const int l = t & 63, w = t >> 6;
    const int li = l & 15, lg = l >> 4;
    const int pu = (w << 3) + (l >> 3);  // staging pixel (one per lane)
    const int g  = l & 7;                // 16B channel-group (8 channels)
    const int b = blockIdx.x;
    const int p0 = blockIdx.y << 6;

    f32x4 acc[2][4];
#pragma unroll
    for (int a = 0; a < 2; ++a)
#pragma unroll
        for (int q = 0; q < 4; ++q) acc[a][q] = (f32x4)0.f;

    const uint32_t* xb = xh + ((size_t)b << 19);   // b*4096*128 dwords

    for (int j = t; j < 576; j += 512)
        ml[j >> 6][j & 63] = mpack[((b * 9 + (j >> 6)) << 12) + p0 + (j & 63)];
    __syncthreads();

    auto STAGE = [&](int s) {
        const int k = s % 9, ch = s / 9;
        const int4 m = ml[k][pu];
        const int i00 = m.x & 0xFFFF, i01 = ((unsigned)m.x) >> 16;
        const int i10 = m.y & 0xFFFF, i11 = ((unsigned)m.y) >> 16;
        union { int i; __half2 h; } uz, uw;
        uz.i = m.z; uw.i = m.w;
        const uint32_t* base = xb + (ch << 5) + (g << 2);
        uint4 v00 = *(const uint4*)(base + (size_t)i00 * 128);
        uint4 v01 = *(const uint4*)(base + (size_t)i01 * 128);
        uint4 v10 = *(const uint4*)(base + (size_t)i10 * 128);
        uint4 v11 = *(const uint4*)(base + (size_t)i11 * 128);
        const __half2 w00 = __half2half2(__low2half(uz.h));
        const __half2 w01 = __half2half2(__high2half(uz.h));
        const __half2 w10 = __half2half2(__low2half(uw.h));
        const __half2 w11 = __half2half2(__high2half(uw.h));
        uint4 rr;
        {
            __half2 r = __hmul2(w00, *(__half2*)&v00.x);
            r = __hfma2(w01, *(__half2*)&v01.x, r);
            r = __hfma2(w10, *(__half2*)&v10.x, r);
            r = __hfma2(w11, *(__half2*)&v11.x, r);
            rr.x = *(uint32_t*)&r;
        }
        {
            __half2 r = __hmul2(w00, *(__half2*)&v00.y);
            r = __hfma2(w01, *(__half2*)&v01.y, r);
            r = __hfma2(w10, *(__half2*)&v10.y, r);
            r = __hfma2(w11, *(__half2*)&v11.y, r);
            rr.y = *(uint32_t*)&r;
        }
        {
            __half2 r = __hmul2(w00, *(__half2*)&v00.z);
            r = __hfma2(w01, *(__half2*)&v01.z, r);
            r = __hfma2(w10, *(__half2*)&v10.z, r);
            r = __hfma2(w11, *(__half2*)&v11.z, r);
            rr.z = *(uint32_t*)&r;
        }
        {
            __half2 r = __hmul2(w00, *(__half2*)&v00.w);
            r = __hfma2(w01, *(__half2*)&v01.w, r);
            r = __hfma2(w10, *(__half2*)&v10.w, r);
            r = __hfma2(w11, *(__half2*)&v11.w, r);
            rr.w = *(uint32_t*)&r;
        }
        *(uint4*)&sl[(s >> 1) & 1][s & 1][pu][(g ^ (pu & 7)) << 3] = rr;
    };

    auto COMPUTE = [&](int s) {
        const int k = s % 9, ch = s / 9;
        const ushort* wp = wB + ((size_t)((k * 16 + 2 * w) * 512 + ch * 128)) * 8;
#pragma unroll
        for (int h = 0; h < 2; ++h) {
            frag_h bq[4];
#pragma unroll
            for (int pt = 0; pt < 4; ++pt)
                bq[pt] = *(const frag_h*)&sl[(s >> 1) & 1][s & 1][pt * 16 + li]
                                           [((((h << 2) | lg) ^ (l & 7)) << 3)];
#pragma unroll
            for (int ft = 0; ft < 2; ++ft) {
                frag_h a = *(const frag_h*)(wp + (size_t)(ft * 512 + h * 64 + l) * 8);
#pragma unroll
                for (int pt = 0; pt < 4; ++pt)
                    acc[ft][pt] = __builtin_amdgcn_mfma_f32_16x16x32_f16(
                        a, bq[pt], acc[ft][pt], 0, 0, 0);
            }
        }
    };

    STAGE(0);
    STAGE(1);
    __syncthreads();
#pragma unroll 1
    for (int s = 0; s < 36; s += 2) {
        if (s + 2 < 36) {
            STAGE(s + 2);
            STAGE(s + 3);
        }
        COMPUTE(s);
        COMPUTE(s + 1);
        __syncthreads();
    }

    float* ob = out + (size_t)b * Fn * HWn + p0;
#pragma unroll
    for (int ft = 0; ft < 2; ++ft)
#pragma unroll
        for (int j = 0; j < 4; ++j) {
            int f = w * 32 + ft * 16 + lg * 4 + j;
#pragma unroll
            for (int pt = 0; pt < 4; ++pt)
                ob[(size_t)f * HWn + pt * 16 + li] = acc[ft][pt][j];
        }
}

extern "C" void kernel_launch(void* const* d_in, const int* in_sizes, int n_in,
                              void* d_out, int out_size, void* d_ws, size_t ws_size,
                              hipStream_t stream) {
    const float* x  = (const float*)d_in[0];
    const float* wo = (const float*)d_in[1];
    const float* wm = (const float*)d_in[2];
    const float* wd = (const float*)d_in[3];
    float* out = (float*)d_out;

    // ws (no overlays): [mpack 4.72MB][wB 1.18MB][xh 16.78MB][wA27 147KB]
    int4*     mpack = (int4*)d_ws;
    ushort*   wBp   = (ushort*)((char*)d_ws + 4718592);
    __half2*  xhh   = (__half2*)((char*)d_ws + 5898240);
    uint32_t* xhu   = (uint32_t*)((char*)d_ws + 5898240);
    ushort*   wA27  = (ushort*)((char*)d_ws + 22675456);

    packall<<<dim3(3104), dim3(256), 0, stream>>>(wd, wo, wm, x, wBp, wA27, xhh);
    offmeta<<<dim3(Bn, 32), dim3(512), 0, stream>>>(xhu, wA27, mpack);
    dconv<<<dim3(Bn, HWn / 64), dim3(512), 0, stream>>>(xhu, wBp, mpack, out);
}